// Round 4
// baseline (161.375 us; speedup 1.0000x reference)
//
#include <hip/hip_runtime.h>
#include <hip/hip_bf16.h>
#include <stdint.h>

#define B_ 32
#define S_ 512
#define D_ 768
#define O_ 768
#define E_ 8
#define YSIZE (B_ * S_ * O_)   // 12582912
#define BK 32
#define NSTEP (D_ / BK)        // 24
#define WSLICE (O_ * D_)       // 589824 elements per expert / per-b combined slice

typedef __attribute__((ext_vector_type(8))) short bf16x8;
typedef __attribute__((ext_vector_type(4))) float f32x4;

static __device__ __forceinline__ unsigned short f2bf(float f) {
  union { float f; uint32_t u; } v; v.f = f;
  uint32_t u = v.u;
  uint32_t r = u + 0x7fff + ((u >> 16) & 1);   // RNE
  return (unsigned short)(r >> 16);
}

static __device__ __forceinline__ void async_load16(const void* g, void* l) {
  __builtin_amdgcn_global_load_lds(
      (const __attribute__((address_space(1))) void*)g,
      (__attribute__((address_space(3))) void*)l, 16, 0, 0);
}

// ---------------- Kernel 1: pool partial sums + x -> bf16 ----------------
// grid (32, 16), block 192 (3 waves): thread t owns d = 4t..4t+3 (float4).
// psum layout: [b][chunk][d] so k_logits reads contiguous.
__global__ __launch_bounds__(192) void k_pool_convert(
    const float* __restrict__ x, unsigned short* __restrict__ xb,
    float* __restrict__ psum) {
  int t  = threadIdx.x;          // 0..191
  int b  = blockIdx.x;
  int sc = blockIdx.y;           // 0..15, 32 s-rows each
  size_t rowbase = (size_t)(b * S_ + sc * 32) * D_;
  const float* xp = x + rowbase + 4 * t;
  unsigned short* op = xb + rowbase + 4 * t;
  float4 sum = {0.f, 0.f, 0.f, 0.f};
  #pragma unroll 8
  for (int s = 0; s < 32; ++s) {
    float4 v = *(const float4*)(xp + (size_t)s * D_);
    sum.x += v.x; sum.y += v.y; sum.z += v.z; sum.w += v.w;
    ushort4 o;
    o.x = f2bf(v.x); o.y = f2bf(v.y); o.z = f2bf(v.z); o.w = f2bf(v.w);
    *(ushort4*)(op + (size_t)s * D_) = o;
  }
  *(float4*)(psum + (size_t)(b * 16 + sc) * D_ + 4 * t) = sum;
}

// ---------------- Kernel 2a: logits + top-2 + softmax (one block per b) ----
__global__ __launch_bounds__(256) void k_logits(
    const float* __restrict__ psum, const float* __restrict__ w_gate,
    float* __restrict__ gates, int* __restrict__ eidx,
    float* __restrict__ gval) {
  int b = blockIdx.x;
  int tid = threadIdx.x;
  float acc[E_];
  #pragma unroll
  for (int e = 0; e < E_; ++e) acc[e] = 0.f;

  for (int d = tid; d < D_; d += 256) {
    float p = 0.f;
    #pragma unroll
    for (int c = 0; c < 16; ++c) p += psum[(size_t)(b * 16 + c) * D_ + d];
    p *= (1.0f / (float)S_);
    const float* wg = w_gate + d * E_;
    #pragma unroll
    for (int e = 0; e < E_; ++e) acc[e] += p * wg[e];
  }
  #pragma unroll
  for (int off = 32; off > 0; off >>= 1) {
    #pragma unroll
    for (int e = 0; e < E_; ++e) acc[e] += __shfl_down(acc[e], off, 64);
  }
  __shared__ float part[4][E_];
  if ((tid & 63) == 0) {
    #pragma unroll
    for (int e = 0; e < E_; ++e) part[tid >> 6][e] = acc[e];
  }
  __syncthreads();
  if (tid == 0) {
    float lg[E_];
    #pragma unroll
    for (int e = 0; e < E_; ++e)
      lg[e] = part[0][e] + part[1][e] + part[2][e] + part[3][e];
    int i0 = 0; float v0 = lg[0];
    #pragma unroll
    for (int e = 1; e < E_; ++e) { if (lg[e] > v0) { v0 = lg[e]; i0 = e; } }
    int i1 = -1; float v1 = -1e30f;
    #pragma unroll
    for (int e = 0; e < E_; ++e) {
      if (e == i0) continue;
      if (lg[e] > v1) { v1 = lg[e]; i1 = e; }
    }
    float m  = fmaxf(v0, v1);
    float x0 = expf(v0 - m), x1 = expf(v1 - m);
    float s  = x0 + x1;
    float g0 = x0 / s, g1 = x1 / s;
    #pragma unroll
    for (int e = 0; e < E_; ++e)
      gates[b * E_ + e] = (e == i0) ? g0 : ((e == i1) ? g1 : 0.f);
    eidx[b] = i0; eidx[B_ + b] = i1;
    gval[b] = g0; gval[B_ + b] = g1;
  }
}

// ---------------- Kernel 2c: combined weights + fused aux loss ------------
// R6: grid 576, block 256. Each thread owns 4 consecutive weight elements
// (float4) and loops over ALL 32 b — weight tensor is read ONCE (18.9 MB)
// instead of 4x (75 MB). Writes unchanged (37.7 MB). Predicted: FETCH_SIZE
// for this dispatch ~4x lower, dur -30..40%.
__global__ __launch_bounds__(256) void k_combine(
    const float* __restrict__ weight, const float* __restrict__ gates,
    unsigned short* __restrict__ wc, float* __restrict__ loss_out) {
  __shared__ float gsh[B_][E_];
  int tid = threadIdx.x;
  if (tid < B_ * E_) ((float*)gsh)[tid] = gates[tid];
  __syncthreads();

  if (blockIdx.x == 0 && tid == 0) {
    double mi = 0, ml = 0;
    float imp[E_], ldv[E_];
    #pragma unroll
    for (int e = 0; e < E_; ++e) {
      float s = 0.f, c = 0.f;
      for (int b = 0; b < B_; ++b) {
        float g = gsh[b][e];
        s += g; c += (g > 0.f) ? 1.f : 0.f;
      }
      imp[e] = s; ldv[e] = c;
      mi += s; ml += c;
    }
    mi /= E_; ml /= E_;
    double vi = 0, vl = 0;
    #pragma unroll
    for (int e = 0; e < E_; ++e) {
      double di = imp[e] - mi, dl = ldv[e] - ml;
      vi += di * di; vl += dl * dl;
    }
    vi /= (E_ - 1); vl /= (E_ - 1);
    loss_out[0] = (float)((vi / (mi * mi + 1e-10) + vl / (ml * ml + 1e-10)) * 0.01);
  }

  size_t i = (size_t)blockIdx.x * 1024 + (size_t)tid * 4;
  float v[E_][4];
  #pragma unroll
  for (int e = 0; e < E_; ++e) {
    float4 u = *(const float4*)(weight + (size_t)e * WSLICE + i);
    v[e][0] = u.x; v[e][1] = u.y; v[e][2] = u.z; v[e][3] = u.w;
  }
  #pragma unroll 4
  for (int b = 0; b < B_; ++b) {
    float c[4];
    #pragma unroll
    for (int j = 0; j < 4; ++j) c[j] = 0.f;
    #pragma unroll
    for (int e = 0; e < E_; ++e) {
      float g = gsh[b][e];
      #pragma unroll
      for (int j = 0; j < 4; ++j) c[j] += g * v[e][j];
    }
    uint32_t p0 = (uint32_t)f2bf(c[0]) | ((uint32_t)f2bf(c[1]) << 16);
    uint32_t p1 = (uint32_t)f2bf(c[2]) | ((uint32_t)f2bf(c[3]) << 16);
    *(uint2*)(wc + (size_t)b * WSLICE + i) = make_uint2(p0, p1);
  }
}

// ---------------- Kernel 3: batched GEMM y[b] = x[b] @ Wc[b]^T + bias ------
// R6: prefetch-pipelined double-buffer (T3-min recipe). K-step dropped from
// 64 to 32 so the two LDS buffers alternate across K-steps at the same
// 32 KB total (keeps 3 blocks/CU). Per iteration: issue tile t+1's 4 DMAs
// -> ds_read + 16 MFMA on tile t -> one vmcnt(0)+barrier. The DMA latency
// (mostly L2-hit: per-b working set ~2 MB, XCD-affine grid) now hides under
// the compute phase instead of serializing. Same 16B-segment XOR swizzle on
// both stage-source and fragment-read (involution unchanged).
__global__ __launch_bounds__(256, 3) void k_moe_gemm(
    const unsigned short* __restrict__ xb, const unsigned short* __restrict__ wc,
    const int* __restrict__ eidx, const float* __restrict__ gval,
    const float* __restrict__ bias, float* __restrict__ y) {
  __shared__ unsigned short Alds[2][128 * BK];  // 2 x 8 KB
  __shared__ unsigned short Blds[2][128 * BK];  // 2 x 8 KB

  int flat = blockIdx.x;          // 0..767
  int xcd  = flat & 7;
  int slot = flat >> 3;           // 0..95
  int b    = xcd + 8 * (slot / 24);
  int tile = slot % 24;
  int st = tile & 3;              // S tile 0..3
  int ot = tile >> 2;             // O tile 0..5
  int s0 = st * 128, o0 = ot * 128;

  int tid  = threadIdx.x;
  int wave = tid >> 6, lane = tid & 63;
  int wm = wave & 1, wn = wave >> 1;

  const unsigned short* Abase = xb + ((size_t)(b * S_ + s0)) * D_;
  const unsigned short* Bbase = wc + (size_t)b * WSLICE + (size_t)o0 * D_;

  f32x4 acc[4][4];
  #pragma unroll
  for (int i = 0; i < 4; ++i)
    #pragma unroll
    for (int j = 0; j < 4; ++j) acc[i][j] = (f32x4){0.f, 0.f, 0.f, 0.f};

  int a_chunk0 = wave * 2;
  int a_r = lane >> 2;                              // row within 16-row chunk
  int a_c = (((lane & 3) ^ ((a_r >> 1) & 3))) * 8;  // swizzled source column

  // fragment-read addressing
  int sseg  = lane >> 4;                    // logical 16B segment (k/8)
  int r16   = lane & 15;
  int kphys = (sseg ^ ((r16 >> 1) & 3)) * 8;  // swizzled physical segment

  auto stage = [&](int buf, int kk) {
    #pragma unroll
    for (int j = 0; j < 2; ++j) {
      int chunk = a_chunk0 + j;
      const unsigned short* srcA =
          Abase + (size_t)(chunk * 16 + a_r) * D_ + kk + a_c;
      async_load16(srcA, &Alds[buf][chunk * 512]);
      const unsigned short* srcB =
          Bbase + (size_t)(chunk * 16 + a_r) * D_ + kk + a_c;
      async_load16(srcB, &Blds[buf][chunk * 512]);
    }
  };

  auto compute = [&](int buf) {
    bf16x8 af[4], bfr[4];
    #pragma unroll
    for (int mi = 0; mi < 4; ++mi)
      af[mi] = *(const bf16x8*)(&Alds[buf][(wm * 64 + mi * 16 + r16) * BK + kphys]);
    #pragma unroll
    for (int ni = 0; ni < 4; ++ni)
      bfr[ni] = *(const bf16x8*)(&Blds[buf][(wn * 64 + ni * 16 + r16) * BK + kphys]);
    #pragma unroll
    for (int mi = 0; mi < 4; ++mi)
      #pragma unroll
      for (int ni = 0; ni < 4; ++ni)
        acc[mi][ni] = __builtin_amdgcn_mfma_f32_16x16x32_bf16(
            af[mi], bfr[ni], acc[mi][ni], 0, 0, 0);
  };

  // prologue: stage tile 0
  stage(0, 0);
  __syncthreads();   // compiler emits vmcnt(0) drain before s_barrier

  // steady state: tiles 0..21 in pairs (buf index is compile-time constant)
  #pragma unroll 1
  for (int tt = 0; tt < 11; ++tt) {
    stage(1, (2 * tt + 1) * BK);
    compute(0);                  // tile 2*tt
    __syncthreads();
    stage(0, (2 * tt + 2) * BK);
    compute(1);                  // tile 2*tt+1
    __syncthreads();
  }
  // tiles 22, 23
  stage(1, 23 * BK);
  compute(0);                    // tile 22
  __syncthreads();
  compute(1);                    // tile 23

  // --- epilogue: y = acc + g0*bias[e0] + g1*bias[e1] ---
  int   e0 = eidx[b], e1 = eidx[B_ + b];
  float g0 = gval[b], g1 = gval[B_ + b];
  float* Y = y + ((size_t)(b * S_ + s0)) * O_ + o0;
  int col   = lane & 15;
  int rquad = (lane >> 4) * 4;
  #pragma unroll
  for (int ni = 0; ni < 4; ++ni) {
    int n = wn * 64 + ni * 16 + col;
    float cbv = g0 * bias[e0 * O_ + o0 + n] + g1 * bias[e1 * O_ + o0 + n];
    #pragma unroll
    for (int mi = 0; mi < 4; ++mi) {
      #pragma unroll
      for (int r = 0; r < 4; ++r) {
        int m = wm * 64 + mi * 16 + rquad + r;
        Y[(size_t)m * O_ + n] = acc[mi][ni][r] + cbv;
      }
    }
  }
}

// ---------------- launcher ----------------
// ws layout (bytes):
//   [0,        1572864)  psum   float[32*16*768]
//   [1572864,  1573888)  gates  float[32*8]
//   [1573888,  1574144)  eidx   int[64]
//   [1574144,  1574400)  gval   float[64]
//   [2097152, 27262976)  x_bf16 ushort[32*512*768]   (25.2 MB)
//   [27262976,65011712)  wc     ushort[32*768*768]   (37.7 MB)
extern "C" void kernel_launch(void* const* d_in, const int* in_sizes, int n_in,
                              void* d_out, int out_size, void* d_ws, size_t ws_size,
                              hipStream_t stream) {
  const float* x      = (const float*)d_in[0];
  const float* w_gate = (const float*)d_in[1];
  const float* weight = (const float*)d_in[2];
  const float* bias   = (const float*)d_in[3];
  float* y = (float*)d_out;

  float* psum  = (float*)d_ws;
  float* gates = (float*)((char*)d_ws + 1572864);
  int*   eidx  = (int*)((char*)d_ws + 1573888);
  float* gval  = (float*)((char*)d_ws + 1574144);
  unsigned short* xb = (unsigned short*)((char*)d_ws + 2097152);
  unsigned short* wc = (unsigned short*)((char*)d_ws + 27262976);

  k_pool_convert<<<dim3(32, 16), 192, 0, stream>>>(x, xb, psum);
  k_logits<<<32, 256, 0, stream>>>(psum, w_gate, gates, eidx, gval);
  k_combine<<<576, 256, 0, stream>>>(weight, gates, wc, y + YSIZE);
  k_moe_gemm<<<768, 256, 0, stream>>>(xb, wc, eidx, gval, bias, y);
}

// Round 5
// 160.678 us; speedup vs baseline: 1.0043x; 1.0043x over previous
//
#include <hip/hip_runtime.h>
#include <hip/hip_bf16.h>
#include <stdint.h>

#define B_ 32
#define S_ 512
#define D_ 768
#define O_ 768
#define E_ 8
#define YSIZE (B_ * S_ * O_)   // 12582912
#define BK 32
#define NSTEP (D_ / BK)        // 24
#define WSLICE (O_ * D_)       // 589824 elements per expert / per-b combined slice

typedef __attribute__((ext_vector_type(8))) short bf16x8;
typedef __attribute__((ext_vector_type(4))) float f32x4;

static __device__ __forceinline__ unsigned short f2bf(float f) {
  union { float f; uint32_t u; } v; v.f = f;
  uint32_t u = v.u;
  uint32_t r = u + 0x7fff + ((u >> 16) & 1);   // RNE
  return (unsigned short)(r >> 16);
}

static __device__ __forceinline__ void async_load16(const void* g, void* l) {
  __builtin_amdgcn_global_load_lds(
      (const __attribute__((address_space(1))) void*)g,
      (__attribute__((address_space(3))) void*)l, 16, 0, 0);
}

// ---------------- Kernel 1: pool partial sums + x -> bf16 ----------------
// grid (32, 16), block 192 (3 waves): thread t owns d = 4t..4t+3 (float4).
// psum layout: [b][chunk][d] so k_logits reads contiguous.
__global__ __launch_bounds__(192) void k_pool_convert(
    const float* __restrict__ x, unsigned short* __restrict__ xb,
    float* __restrict__ psum) {
  int t  = threadIdx.x;          // 0..191
  int b  = blockIdx.x;
  int sc = blockIdx.y;           // 0..15, 32 s-rows each
  size_t rowbase = (size_t)(b * S_ + sc * 32) * D_;
  const float* xp = x + rowbase + 4 * t;
  unsigned short* op = xb + rowbase + 4 * t;
  float4 sum = {0.f, 0.f, 0.f, 0.f};
  #pragma unroll 8
  for (int s = 0; s < 32; ++s) {
    float4 v = *(const float4*)(xp + (size_t)s * D_);
    sum.x += v.x; sum.y += v.y; sum.z += v.z; sum.w += v.w;
    ushort4 o;
    o.x = f2bf(v.x); o.y = f2bf(v.y); o.z = f2bf(v.z); o.w = f2bf(v.w);
    *(ushort4*)(op + (size_t)s * D_) = o;
  }
  *(float4*)(psum + (size_t)(b * 16 + sc) * D_ + 4 * t) = sum;
}

// ---------------- Kernel 2a: logits + top-2 + softmax (one block per b) ----
__global__ __launch_bounds__(256) void k_logits(
    const float* __restrict__ psum, const float* __restrict__ w_gate,
    float* __restrict__ gates, int* __restrict__ eidx,
    float* __restrict__ gval) {
  int b = blockIdx.x;
  int tid = threadIdx.x;
  float acc[E_];
  #pragma unroll
  for (int e = 0; e < E_; ++e) acc[e] = 0.f;

  for (int d = tid; d < D_; d += 256) {
    float p = 0.f;
    #pragma unroll
    for (int c = 0; c < 16; ++c) p += psum[(size_t)(b * 16 + c) * D_ + d];
    p *= (1.0f / (float)S_);
    const float* wg = w_gate + d * E_;
    #pragma unroll
    for (int e = 0; e < E_; ++e) acc[e] += p * wg[e];
  }
  #pragma unroll
  for (int off = 32; off > 0; off >>= 1) {
    #pragma unroll
    for (int e = 0; e < E_; ++e) acc[e] += __shfl_down(acc[e], off, 64);
  }
  __shared__ float part[4][E_];
  if ((tid & 63) == 0) {
    #pragma unroll
    for (int e = 0; e < E_; ++e) part[tid >> 6][e] = acc[e];
  }
  __syncthreads();
  if (tid == 0) {
    float lg[E_];
    #pragma unroll
    for (int e = 0; e < E_; ++e)
      lg[e] = part[0][e] + part[1][e] + part[2][e] + part[3][e];
    int i0 = 0; float v0 = lg[0];
    #pragma unroll
    for (int e = 1; e < E_; ++e) { if (lg[e] > v0) { v0 = lg[e]; i0 = e; } }
    int i1 = -1; float v1 = -1e30f;
    #pragma unroll
    for (int e = 0; e < E_; ++e) {
      if (e == i0) continue;
      if (lg[e] > v1) { v1 = lg[e]; i1 = e; }
    }
    float m  = fmaxf(v0, v1);
    float x0 = expf(v0 - m), x1 = expf(v1 - m);
    float s  = x0 + x1;
    float g0 = x0 / s, g1 = x1 / s;
    #pragma unroll
    for (int e = 0; e < E_; ++e)
      gates[b * E_ + e] = (e == i0) ? g0 : ((e == i1) ? g1 : 0.f);
    eidx[b] = i0; eidx[B_ + b] = i1;
    gval[b] = g0; gval[B_ + b] = g1;
  }
}

// ---------------- Kernel 2c: combined weights + fused aux loss ------------
// Measured R4: neutral vs 4x-read version — weight (18.9 MB) is L3-resident,
// so the old re-reads were L3 hits; kernel is write-bound (37.7 MB). Keeping
// this simpler 1x-read shape.
__global__ __launch_bounds__(256) void k_combine(
    const float* __restrict__ weight, const float* __restrict__ gates,
    unsigned short* __restrict__ wc, float* __restrict__ loss_out) {
  __shared__ float gsh[B_][E_];
  int tid = threadIdx.x;
  if (tid < B_ * E_) ((float*)gsh)[tid] = gates[tid];
  __syncthreads();

  if (blockIdx.x == 0 && tid == 0) {
    double mi = 0, ml = 0;
    float imp[E_], ldv[E_];
    #pragma unroll
    for (int e = 0; e < E_; ++e) {
      float s = 0.f, c = 0.f;
      for (int b = 0; b < B_; ++b) {
        float g = gsh[b][e];
        s += g; c += (g > 0.f) ? 1.f : 0.f;
      }
      imp[e] = s; ldv[e] = c;
      mi += s; ml += c;
    }
    mi /= E_; ml /= E_;
    double vi = 0, vl = 0;
    #pragma unroll
    for (int e = 0; e < E_; ++e) {
      double di = imp[e] - mi, dl = ldv[e] - ml;
      vi += di * di; vl += dl * dl;
    }
    vi /= (E_ - 1); vl /= (E_ - 1);
    loss_out[0] = (float)((vi / (mi * mi + 1e-10) + vl / (ml * ml + 1e-10)) * 0.01);
  }

  size_t i = (size_t)blockIdx.x * 1024 + (size_t)tid * 4;
  float v[E_][4];
  #pragma unroll
  for (int e = 0; e < E_; ++e) {
    float4 u = *(const float4*)(weight + (size_t)e * WSLICE + i);
    v[e][0] = u.x; v[e][1] = u.y; v[e][2] = u.z; v[e][3] = u.w;
  }
  #pragma unroll 4
  for (int b = 0; b < B_; ++b) {
    float c[4];
    #pragma unroll
    for (int j = 0; j < 4; ++j) c[j] = 0.f;
    #pragma unroll
    for (int e = 0; e < E_; ++e) {
      float g = gsh[b][e];
      #pragma unroll
      for (int j = 0; j < 4; ++j) c[j] += g * v[e][j];
    }
    uint32_t p0 = (uint32_t)f2bf(c[0]) | ((uint32_t)f2bf(c[1]) << 16);
    uint32_t p1 = (uint32_t)f2bf(c[2]) | ((uint32_t)f2bf(c[3]) << 16);
    *(uint2*)(wc + (size_t)b * WSLICE + i) = make_uint2(p0, p1);
  }
}

// ---------------- Kernel 3: batched GEMM y[b] = x[b] @ Wc[b]^T + bias ------
// R4 result: __syncthreads-based prefetch was NEUTRAL (m99/m100 outcome —
// the compiler's vmcnt(0) drain at each barrier nullifies issue-early).
// R5: T4 counted-vmcnt + raw s_barrier. Each thread issues exactly 4 DMAs
// per stage; "s_waitcnt vmcnt(4)" after issuing tile t+1's 4 retires exactly
// tile t's 4 while t+1's stay in flight ACROSS the barrier. Never vmcnt(0)
// in the main loop (m218: the counted wait is the active ingredient).
// Epilogue globals (eidx/gval/bias) are pre-loaded and drained with one
// vmcnt(0) BEFORE the loop so the only loop VMEM ops are the staging DMAs
// (keeps the count exact).
__global__ __launch_bounds__(256, 3) void k_moe_gemm(
    const unsigned short* __restrict__ xb, const unsigned short* __restrict__ wc,
    const int* __restrict__ eidx, const float* __restrict__ gval,
    const float* __restrict__ bias, float* __restrict__ y) {
  __shared__ unsigned short Alds[2][128 * BK];  // 2 x 8 KB
  __shared__ unsigned short Blds[2][128 * BK];  // 2 x 8 KB

  int flat = blockIdx.x;          // 0..767
  int xcd  = flat & 7;
  int slot = flat >> 3;           // 0..95
  int b    = xcd + 8 * (slot / 24);
  int tile = slot % 24;
  int st = tile & 3;              // S tile 0..3
  int ot = tile >> 2;             // O tile 0..5
  int s0 = st * 128, o0 = ot * 128;

  int tid  = threadIdx.x;
  int wave = tid >> 6, lane = tid & 63;
  int wm = wave & 1, wn = wave >> 1;

  const unsigned short* Abase = xb + ((size_t)(b * S_ + s0)) * D_;
  const unsigned short* Bbase = wc + (size_t)b * WSLICE + (size_t)o0 * D_;

  // ---- pre-load ALL epilogue globals, then drain vmcnt to 0 so the loop's
  // vmcnt counting sees only staging DMAs ----
  int   e0 = eidx[b], e1 = eidx[B_ + b];
  float g0 = gval[b], g1 = gval[B_ + b];
  int col   = lane & 15;
  int rquad = (lane >> 4) * 4;
  float cbv[4];
  #pragma unroll
  for (int ni = 0; ni < 4; ++ni) {
    int n = wn * 64 + ni * 16 + col;
    cbv[ni] = g0 * bias[e0 * O_ + o0 + n] + g1 * bias[e1 * O_ + o0 + n];
  }
  asm volatile("s_waitcnt vmcnt(0)" ::: "memory");

  f32x4 acc[4][4];
  #pragma unroll
  for (int i = 0; i < 4; ++i)
    #pragma unroll
    for (int j = 0; j < 4; ++j) acc[i][j] = (f32x4){0.f, 0.f, 0.f, 0.f};

  int a_chunk0 = wave * 2;
  int a_r = lane >> 2;                              // row within 16-row chunk
  int a_c = (((lane & 3) ^ ((a_r >> 1) & 3))) * 8;  // swizzled source column

  // fragment-read addressing
  int sseg  = lane >> 4;                    // logical 16B segment (k/8)
  int r16   = lane & 15;
  int kphys = (sseg ^ ((r16 >> 1) & 3)) * 8;  // swizzled physical segment

  auto stage = [&](int buf, int kk) {   // exactly 4 VMEM ops per thread
    #pragma unroll
    for (int j = 0; j < 2; ++j) {
      int chunk = a_chunk0 + j;
      const unsigned short* srcA =
          Abase + (size_t)(chunk * 16 + a_r) * D_ + kk + a_c;
      async_load16(srcA, &Alds[buf][chunk * 512]);
      const unsigned short* srcB =
          Bbase + (size_t)(chunk * 16 + a_r) * D_ + kk + a_c;
      async_load16(srcB, &Blds[buf][chunk * 512]);
    }
  };

  auto compute = [&](int buf) {
    bf16x8 af[4], bfr[4];
    #pragma unroll
    for (int mi = 0; mi < 4; ++mi)
      af[mi] = *(const bf16x8*)(&Alds[buf][(wm * 64 + mi * 16 + r16) * BK + kphys]);
    #pragma unroll
    for (int ni = 0; ni < 4; ++ni)
      bfr[ni] = *(const bf16x8*)(&Blds[buf][(wn * 64 + ni * 16 + r16) * BK + kphys]);
    #pragma unroll
    for (int mi = 0; mi < 4; ++mi)
      #pragma unroll
      for (int ni = 0; ni < 4; ++ni)
        acc[mi][ni] = __builtin_amdgcn_mfma_f32_16x16x32_bf16(
            af[mi], bfr[ni], acc[mi][ni], 0, 0, 0);
  };

  // "memory" clobber on the waits pins compiler ds_reads/DMAs on the correct
  // side; raw s_barrier does NOT drain vmcnt (unlike __syncthreads).
  #define VM4 asm volatile("s_waitcnt vmcnt(4)" ::: "memory")
  #define VM0 asm volatile("s_waitcnt vmcnt(0)" ::: "memory")
  #define BARx __builtin_amdgcn_s_barrier()

  // prologue: stage tile 0 into buf0 (4 ops in flight)
  stage(0, 0);

  // steady state, tiles 0..21 in pairs (buf index compile-time constant).
  // Invariant at each VM4: outstanding = 8 (prev tile's 4 + next tile's 4);
  // waiting to 4 retires exactly the tile about to be computed.
  #pragma unroll 1
  for (int tt = 0; tt < 11; ++tt) {
    stage(1, (2 * tt + 1) * BK);
    VM4; BARx;
    compute(0);                  // tile 2*tt
    BARx;                        // all readers of buf0 done before restage
    stage(0, (2 * tt + 2) * BK);
    VM4; BARx;
    compute(1);                  // tile 2*tt+1
    BARx;
  }
  // tile 22 (in buf0, staged at tt=10) + tile 23
  stage(1, 23 * BK);
  VM4; BARx;
  compute(0);                    // tile 22
  VM0; BARx;                     // drain tile 23's loads
  compute(1);                    // tile 23

  #undef VM4
  #undef VM0
  #undef BARx

  // --- epilogue: y = acc + cbv (bias pre-combined) ---
  float* Y = y + ((size_t)(b * S_ + s0)) * O_ + o0;
  #pragma unroll
  for (int ni = 0; ni < 4; ++ni) {
    int n = wn * 64 + ni * 16 + col;
    #pragma unroll
    for (int mi = 0; mi < 4; ++mi) {
      #pragma unroll
      for (int r = 0; r < 4; ++r) {
        int m = wm * 64 + mi * 16 + rquad + r;
        Y[(size_t)m * O_ + n] = acc[mi][ni][r] + cbv[ni];
      }
    }
  }
}

// ---------------- launcher ----------------
// ws layout (bytes):
//   [0,        1572864)  psum   float[32*16*768]
//   [1572864,  1573888)  gates  float[32*8]
//   [1573888,  1574144)  eidx   int[64]
//   [1574144,  1574400)  gval   float[64]
//   [2097152, 27262976)  x_bf16 ushort[32*512*768]   (25.2 MB)
//   [27262976,65011712)  wc     ushort[32*768*768]   (37.7 MB)
extern "C" void kernel_launch(void* const* d_in, const int* in_sizes, int n_in,
                              void* d_out, int out_size, void* d_ws, size_t ws_size,
                              hipStream_t stream) {
  const float* x      = (const float*)d_in[0];
  const float* w_gate = (const float*)d_in[1];
  const float* weight = (const float*)d_in[2];
  const float* bias   = (const float*)d_in[3];
  float* y = (float*)d_out;

  float* psum  = (float*)d_ws;
  float* gates = (float*)((char*)d_ws + 1572864);
  int*   eidx  = (int*)((char*)d_ws + 1573888);
  float* gval  = (float*)((char*)d_ws + 1574144);
  unsigned short* xb = (unsigned short*)((char*)d_ws + 2097152);
  unsigned short* wc = (unsigned short*)((char*)d_ws + 27262976);

  k_pool_convert<<<dim3(32, 16), 192, 0, stream>>>(x, xb, psum);
  k_logits<<<32, 256, 0, stream>>>(psum, w_gate, gates, eidx, gval);
  k_combine<<<576, 256, 0, stream>>>(weight, gates, wc, y + YSIZE);
  k_moe_gemm<<<768, 256, 0, stream>>>(xb, wc, eidx, gval, bias, y);
}